// Round 1
// baseline (106.623 us; speedup 1.0000x reference)
//
#include <hip/hip_runtime.h>

#define NQ 4
#define NL 3
#define NPARAM (NL * NQ * 2)   // 24

__global__ __launch_bounds__(256) void vqc_kernel(const float* __restrict__ patch,
                                                  const float* __restrict__ params,
                                                  float* __restrict__ out,
                                                  int B) {
    // --- shared trig of the batch-uniform params (half-angles) ---
    __shared__ float s_c[NPARAM];
    __shared__ float s_s[NPARAM];
    int tid = threadIdx.x;
    if (tid < NPARAM) {
        float ang = 0.5f * params[tid];
        float sv, cv;
        __sincosf(ang, &sv, &cv);
        s_c[tid] = cv;
        s_s[tid] = sv;
    }
    __syncthreads();

    int i = blockIdx.x * blockDim.x + tid;
    if (i >= B) return;

    // --- coalesced float4 load of this element's 4 patch angles ---
    float4 p = reinterpret_cast<const float4*>(patch)[i];
    float c0, s0, c1, s1, c2, s2, c3, s3;
    __sincosf(0.5f * p.x, &s0, &c0);
    __sincosf(0.5f * p.y, &s1, &c1);
    __sincosf(0.5f * p.z, &s2, &c2);
    __sincosf(0.5f * p.w, &s3, &c3);

    // --- initial state: product of per-qubit [cos, sin] (all-real) ---
    // flat index k: wire w -> bit mask (8 >> w)
    float re[16], im[16];
#pragma unroll
    for (int k = 0; k < 16; ++k) {
        float a = ((k >> 3) & 1) ? s0 : c0;
        a *= ((k >> 2) & 1) ? s1 : c1;
        a *= ((k >> 1) & 1) ? s2 : c2;
        a *= (k & 1) ? s3 : c3;
        re[k] = a;
        im[k] = 0.0f;
    }

    // --- layers ---
#pragma unroll
    for (int l = 0; l < NL; ++l) {
#pragma unroll
        for (int w = 0; w < NQ; ++w) {
            const int m = 8 >> w;                 // bit mask for wire w
            const float cy = s_c[l * 8 + w * 2 + 0];
            const float sy = s_s[l * 8 + w * 2 + 0];
            const float cz = s_c[l * 8 + w * 2 + 1];
            const float sz = s_s[l * 8 + w * 2 + 1];

            // RY(theta): [[c,-s],[s,c]] applied to (amp0, amp1) pairs
#pragma unroll
            for (int base = 0; base < 16; ++base) {
                if (base & m) continue;
                const int j = base | m;
                float r0 = re[base], r1 = re[j];
                float i0 = im[base], i1 = im[j];
                re[base] = cy * r0 - sy * r1;
                re[j]    = sy * r0 + cy * r1;
                im[base] = cy * i0 - sy * i1;
                im[j]    = sy * i0 + cy * i1;
            }
            // RZ(theta): bit0 amp *= (cz - i sz), bit1 amp *= (cz + i sz)
#pragma unroll
            for (int k = 0; k < 16; ++k) {
                float r = re[k], q = im[k];
                if (k & m) {
                    re[k] = r * cz - q * sz;
                    im[k] = q * cz + r * sz;
                } else {
                    re[k] = r * cz + q * sz;
                    im[k] = q * cz - r * sz;
                }
            }
        }
        // CNOT chain: control w, target w+1 -> swap target bit where control=1
#pragma unroll
        for (int w = 0; w < NQ - 1; ++w) {
            const int cm = 8 >> w;
            const int tm = 8 >> (w + 1);
#pragma unroll
            for (int base = 0; base < 16; ++base) {
                if ((base & cm) && !(base & tm)) {
                    const int j = base | tm;
                    float tr = re[base]; re[base] = re[j]; re[j] = tr;
                    float ti = im[base]; im[base] = im[j]; im[j] = ti;
                }
            }
        }
    }

    // --- probabilities and <Z_w> ---
    float ev0 = 0.f, ev1 = 0.f, ev2 = 0.f, ev3 = 0.f;
#pragma unroll
    for (int k = 0; k < 16; ++k) {
        float pk = re[k] * re[k] + im[k] * im[k];
        ev0 += (k & 8) ? -pk : pk;
        ev1 += (k & 4) ? -pk : pk;
        ev2 += (k & 2) ? -pk : pk;
        ev3 += (k & 1) ? -pk : pk;
    }

    float4 o = make_float4(ev0, ev1, ev2, ev3);
    reinterpret_cast<float4*>(out)[i] = o;
}

extern "C" void kernel_launch(void* const* d_in, const int* in_sizes, int n_in,
                              void* d_out, int out_size, void* d_ws, size_t ws_size,
                              hipStream_t stream) {
    const float* patch  = (const float*)d_in[0];
    const float* params = (const float*)d_in[1];
    float* out = (float*)d_out;
    const int B = in_sizes[0] / 4;

    const int block = 256;
    const int grid = (B + block - 1) / block;
    vqc_kernel<<<grid, block, 0, stream>>>(patch, params, out, B);
}

// Round 2
// 91.399 us; speedup vs baseline: 1.1666x; 1.1666x over previous
//
#include <hip/hip_runtime.h>

// 4-qubit, 3-layer variational circuit, B = 2^20 elements, one thread each.
// Wire w <-> bit mask (8 >> w) of the flat amplitude index.
//
// Algebraic restructure vs naive gate-by-gate:
//  - patch RY(p_w) and layer-0 RY(q_w) merge: RY(p+q); state stays a product
//    state through all layer-0 single-qubit gates -> build 16 complex amps
//    via an outer-product tree (24 complex muls) instead of 8 gate passes.
//  - layer-2 RZ dropped: diagonal phases followed only by a CNOT permutation
//    cannot change |amp|^2.
//  - CNOTs are compile-time register renames (free).
//  - <Z_w> sums via shared-subexpression butterfly (40 adds vs 64).

__global__ __launch_bounds__(256) void vqc_kernel(const float* __restrict__ patch,
                                                  const float* __restrict__ params,
                                                  float* __restrict__ out,
                                                  int B) {
    // s_trig[l*4+w] = (cos, sin of 0.5*params[l,w,0],  cos, sin of 0.5*params[l,w,1])
    __shared__ float4 s_trig[12];
    const int tid = threadIdx.x;
    if (tid < 24) {
        const int l = tid >> 3, r = tid & 7;
        const int w = r >> 1, which = r & 1;
        float sv, cv;
        __sincosf(0.5f * params[tid], &sv, &cv);
        float* slot = reinterpret_cast<float*>(&s_trig[l * 4 + w]);
        slot[which * 2 + 0] = cv;
        slot[which * 2 + 1] = sv;
    }
    __syncthreads();

    const int i = blockIdx.x * blockDim.x + tid;
    if (i >= B) return;

    const float4 p = reinterpret_cast<const float4*>(patch)[i];

    // ---- merged RY half-angles: 0.5*(patch[w] + params[0,w,0]) ----
    float cy[4], sy[4];
    __sincosf(0.5f * p.x + 0.5f * params[0], &sy[0], &cy[0]);
    __sincosf(0.5f * p.y + 0.5f * params[2], &sy[1], &cy[1]);
    __sincosf(0.5f * p.z + 0.5f * params[4], &sy[2], &cy[2]);
    __sincosf(0.5f * p.w + 0.5f * params[6], &sy[3], &cy[3]);

    // ---- layer-0 RZ phases -> per-wire complex 2-vectors ----
    // u_w = ( cy*e^{-i hz}, sy*e^{+i hz} )
    float ur[4][2], ui[4][2];
#pragma unroll
    for (int w = 0; w < 4; ++w) {
        const float4 t = s_trig[w];           // t.z = cos(hz), t.w = sin(hz)
        ur[w][0] = cy[w] * t.z;  ui[w][0] = -cy[w] * t.w;
        ur[w][1] = sy[w] * t.z;  ui[w][1] =  sy[w] * t.w;
    }

    // ---- outer-product tree: (u0 x u1), (u2 x u3), then full 16 amps ----
    float ar[4], ai[4], br[4], bi[4];
#pragma unroll
    for (int b0 = 0; b0 < 2; ++b0) {
#pragma unroll
        for (int b1 = 0; b1 < 2; ++b1) {
            const int j = b0 * 2 + b1;
            ar[j] = ur[0][b0] * ur[1][b1] - ui[0][b0] * ui[1][b1];
            ai[j] = ur[0][b0] * ui[1][b1] + ui[0][b0] * ur[1][b1];
            br[j] = ur[2][b0] * ur[3][b1] - ui[2][b0] * ui[3][b1];
            bi[j] = ur[2][b0] * ui[3][b1] + ui[2][b0] * ur[3][b1];
        }
    }

    float re[16], im[16];
#pragma unroll
    for (int hi = 0; hi < 4; ++hi) {
#pragma unroll
        for (int lo = 0; lo < 4; ++lo) {
            const int k = hi * 4 + lo;   // bit3=wire0 ... bit0=wire3
            re[k] = ar[hi] * br[lo] - ai[hi] * bi[lo];
            im[k] = ar[hi] * bi[lo] + ai[hi] * br[lo];
        }
    }

    // ---- layer-0 CNOT chain (register renames) ----
#pragma unroll
    for (int w = 0; w < 3; ++w) {
        const int cm = 8 >> w, tm = 8 >> (w + 1);
#pragma unroll
        for (int base = 0; base < 16; ++base) {
            if ((base & cm) && !(base & tm)) {
                const int j = base | tm;
                float tr = re[base]; re[base] = re[j]; re[j] = tr;
                float ti = im[base]; im[base] = im[j]; im[j] = ti;
            }
        }
    }

    // ---- layers 1 and 2 ----
#pragma unroll
    for (int l = 1; l < 3; ++l) {
#pragma unroll
        for (int w = 0; w < 4; ++w) {
            const int m = 8 >> w;
            const float4 t = s_trig[l * 4 + w];   // (cy, sy, cz, sz)

            // RY (real rotation on pairs, applied to re and im independently)
#pragma unroll
            for (int base = 0; base < 16; ++base) {
                if (base & m) continue;
                const int j = base | m;
                const float r0 = re[base], r1 = re[j];
                const float i0 = im[base], i1 = im[j];
                re[base] = t.x * r0 - t.y * r1;
                re[j]    = t.y * r0 + t.x * r1;
                im[base] = t.x * i0 - t.y * i1;
                im[j]    = t.y * i0 + t.x * i1;
            }

            // RZ — skipped for the final layer (pure phase before a CNOT
            // permutation; probabilities invariant).
            if (l != 2) {
#pragma unroll
                for (int k = 0; k < 16; ++k) {
                    const float r = re[k], q = im[k];
                    if (k & m) {
                        re[k] = r * t.z - q * t.w;
                        im[k] = q * t.z + r * t.w;
                    } else {
                        re[k] = r * t.z + q * t.w;
                        im[k] = q * t.z - r * t.w;
                    }
                }
            }
        }
        // CNOT chain
#pragma unroll
        for (int w = 0; w < 3; ++w) {
            const int cm = 8 >> w, tm = 8 >> (w + 1);
#pragma unroll
            for (int base = 0; base < 16; ++base) {
                if ((base & cm) && !(base & tm)) {
                    const int j = base | tm;
                    float tr = re[base]; re[base] = re[j]; re[j] = tr;
                    float ti = im[base]; im[base] = im[j]; im[j] = ti;
                }
            }
        }
    }

    // ---- probabilities ----
    float pk[16];
#pragma unroll
    for (int k = 0; k < 16; ++k)
        pk[k] = re[k] * re[k] + im[k] * im[k];

    // ---- butterfly for the four <Z_w> ----
    float a8[8], e3 = 0.f;
#pragma unroll
    for (int j = 0; j < 8; ++j) {
        a8[j] = pk[2 * j] + pk[2 * j + 1];
        e3 += pk[2 * j] - pk[2 * j + 1];
    }
    float a4[4], e2 = 0.f;
#pragma unroll
    for (int j = 0; j < 4; ++j) {
        a4[j] = a8[2 * j] + a8[2 * j + 1];
        e2 += a8[2 * j] - a8[2 * j + 1];
    }
    const float e1 = (a4[0] - a4[1]) + (a4[2] - a4[3]);
    const float e0 = (a4[0] + a4[1]) - (a4[2] + a4[3]);

    reinterpret_cast<float4*>(out)[i] = make_float4(e0, e1, e2, e3);
}

extern "C" void kernel_launch(void* const* d_in, const int* in_sizes, int n_in,
                              void* d_out, int out_size, void* d_ws, size_t ws_size,
                              hipStream_t stream) {
    const float* patch  = (const float*)d_in[0];
    const float* params = (const float*)d_in[1];
    float* out = (float*)d_out;
    const int B = in_sizes[0] / 4;

    const int block = 256;
    const int grid = (B + block - 1) / block;
    vqc_kernel<<<grid, block, 0, stream>>>(patch, params, out, B);
}

// Round 3
// 84.017 us; speedup vs baseline: 1.2691x; 1.0879x over previous
//
#include <hip/hip_runtime.h>

// 4-qubit / 3-layer VQC, B = 2^20, one thread per element.
// Wire w <-> bit mask (8 >> w).
//
// vs R2 kernel:
//  - amplitudes are float2 (re,im) ext-vectors -> backend can emit
//    v_pk_fma_f32 / v_pk_mul_f32 (RY applies identically to re & im).
//  - RZ(t) = global_phase * diag(1, e^{it}): only bit-set amps rotate
//    (8 packed complex muls instead of 16 scalar rotations).
//  - batch-uniform trig precomputed by a tiny setup kernel into d_ws,
//    read with literal uniform indices -> s_load -> SGPR operands
//    (no LDS, no __syncthreads).
//  - final CNOT chain replaced by parity observables:
//    <Z0>, <Z0Z1>, <Z0Z1Z2>, <Z0Z1Z2Z3> of the pre-CNOT state.
//  - layer-2 RZ dropped (diagonal phase, probability-invariant).

typedef float v2 __attribute__((ext_vector_type(2)));

__device__ __forceinline__ v2 cmul(v2 a, v2 b) {
    return (v2){ a.x * b.x - a.y * b.y, a.x * b.y + a.y * b.x };
}

// ws float layout:
//  [0..3]            hy0[w]  = 0.5 * params[0][w][0]   (merged-RY half angle offset)
//  [4 + 8g + 0..4]   cy, sy (half-angle RY), cz, -sz, sz (FULL-angle RZ)
//                    for g = (l-1)*4 + w, l in {1,2}   (layer-2 RZ fields unused)
//  [68 + 4w + 0..1]  cos, sin of FULL angle params[0][w][1]  (layer-0 RZ)
__global__ void vqc_setup(const float* __restrict__ params, float* __restrict__ ws) {
    const int t = threadIdx.x;
    if (t >= 12) return;
    const int l = t >> 2, w = t & 3;
    const float ry = params[(l * 4 + w) * 2 + 0];
    const float rz = params[(l * 4 + w) * 2 + 1];
    if (l == 0) {
        ws[w] = 0.5f * ry;
        ws[68 + 4 * w + 0] = cosf(rz);
        ws[68 + 4 * w + 1] = sinf(rz);
    } else {
        const int base = 4 + 8 * ((l - 1) * 4 + w);
        ws[base + 0] = cosf(0.5f * ry);
        ws[base + 1] = sinf(0.5f * ry);
        ws[base + 2] = cosf(rz);
        ws[base + 3] = -sinf(rz);
        ws[base + 4] = sinf(rz);
    }
}

__global__ __launch_bounds__(256) void vqc_main(const float* __restrict__ patch,
                                                const float* __restrict__ ws,
                                                float* __restrict__ out,
                                                const int B) {
    const int i = blockIdx.x * blockDim.x + threadIdx.x;
    if (i >= B) return;

    const float4 p = reinterpret_cast<const float4*>(patch)[i];

    // merged RY(patch + params[0,w,0]) half-angle trig (per-thread)
    float cy0, sy0, cy1, sy1, cy2, sy2, cy3, sy3;
    __sincosf(fmaf(0.5f, p.x, ws[0]), &sy0, &cy0);
    __sincosf(fmaf(0.5f, p.y, ws[1]), &sy1, &cy1);
    __sincosf(fmaf(0.5f, p.z, ws[2]), &sy2, &cy2);
    __sincosf(fmaf(0.5f, p.w, ws[3]), &sy3, &cy3);

    // layer-0 RZ phases e^{i t_w} (uniform, SGPRs)
    const v2 e0 = (v2){ws[68], ws[69]};
    const v2 e1 = (v2){ws[72], ws[73]};
    const v2 e2 = (v2){ws[76], ws[77]};
    const v2 e3 = (v2){ws[80], ws[81]};

    // per-wire 2-vectors u_w = (cy_w [real], sy_w * e^{i t_w})
    const v2 u0c = sy0 * e0;
    const v2 u1c = sy1 * e1;
    const v2 u2c = sy2 * e2;
    const v2 u3c = sy3 * e3;

    // outer products A = u0 x u1 (wires 0,1), Bv = u2 x u3 (wires 2,3)
    const float A0 = cy0 * cy1;
    const v2   A1 = cy0 * u1c;
    const v2   A2 = cy1 * u0c;
    const v2   A3 = cmul(u0c, u1c);
    const float B0 = cy2 * cy3;
    const v2   B1 = cy2 * u3c;
    const v2   B2 = cy3 * u2c;
    const v2   B3 = cmul(u2c, u3c);

    // full 16 amps: amp[hi*4+lo] = A[hi] * Bv[lo]
    v2 amp[16];
    amp[0]  = (v2){A0 * B0, 0.0f};
    amp[1]  = A0 * B1;
    amp[2]  = A0 * B2;
    amp[3]  = A0 * B3;
    amp[4]  = B0 * A1;
    amp[8]  = B0 * A2;
    amp[12] = B0 * A3;
    amp[5]  = cmul(A1, B1);  amp[6]  = cmul(A1, B2);  amp[7]  = cmul(A1, B3);
    amp[9]  = cmul(A2, B1);  amp[10] = cmul(A2, B2);  amp[11] = cmul(A2, B3);
    amp[13] = cmul(A3, B1);  amp[14] = cmul(A3, B2);  amp[15] = cmul(A3, B3);

    // ---- layer-0 CNOT chain (register renames) ----
#pragma unroll
    for (int w = 0; w < 3; ++w) {
        const int cm = 8 >> w, tm = 4 >> w;
#pragma unroll
        for (int b = 0; b < 16; ++b) {
            if ((b & cm) && !(b & tm)) {
                const int j = b | tm;
                const v2 t = amp[b]; amp[b] = amp[j]; amp[j] = t;
            }
        }
    }

    // ---- layer 1: RY + cheap RZ per wire, then CNOT chain ----
#pragma unroll
    for (int w = 0; w < 4; ++w) {
        const int gb = 4 + 8 * w;
        const float cy = ws[gb], sy = ws[gb + 1], cz = ws[gb + 2];
        const v2 zc = (v2){ws[gb + 3], ws[gb + 4]};   // (-sz, +sz)
        const int m = 8 >> w;
#pragma unroll
        for (int b = 0; b < 16; ++b) {
            if (b & m) continue;
            const int j = b | m;
            const v2 a0 = amp[b], a1 = amp[j];
            amp[b] = a0 * cy - a1 * sy;
            amp[j] = a0 * sy + a1 * cy;
        }
        // RZ ~ diag(1, e^{i t}): rotate only bit-set amps
#pragma unroll
        for (int k = 0; k < 16; ++k) {
            if (!(k & m)) continue;
            const v2 a = amp[k];
            amp[k] = a * cz + a.yx * zc;   // (r cz - q sz, q cz + r sz)
        }
    }
#pragma unroll
    for (int w = 0; w < 3; ++w) {
        const int cm = 8 >> w, tm = 4 >> w;
#pragma unroll
        for (int b = 0; b < 16; ++b) {
            if ((b & cm) && !(b & tm)) {
                const int j = b | tm;
                const v2 t = amp[b]; amp[b] = amp[j]; amp[j] = t;
            }
        }
    }

    // ---- layer 2: RY only (RZ is probability-invariant; CNOTs folded into
    //      the parity observables below) ----
#pragma unroll
    for (int w = 0; w < 4; ++w) {
        const int gb = 4 + 8 * (4 + w);
        const float cy = ws[gb], sy = ws[gb + 1];
        const int m = 8 >> w;
#pragma unroll
        for (int b = 0; b < 16; ++b) {
            if (b & m) continue;
            const int j = b | m;
            const v2 a0 = amp[b], a1 = amp[j];
            amp[b] = a0 * cy - a1 * sy;
            amp[j] = a0 * sy + a1 * cy;
        }
    }

    // ---- probabilities ----
    float pk[16];
#pragma unroll
    for (int k = 0; k < 16; ++k)
        pk[k] = fmaf(amp[k].x, amp[k].x, amp[k].y * amp[k].y);

    // ---- parity observables of the pre-CNOT state ----
    // out0 = <Z0> (bit3), out1 = <Z0Z1> (bit3^bit2),
    // out2 = <Z0Z1Z2> (bit3^bit2^bit1), out3 = <Z0Z1Z2Z3> (full parity)
    float s1[8], d1[8];
#pragma unroll
    for (int j = 0; j < 8; ++j) {
        s1[j] = pk[2 * j] + pk[2 * j + 1];
        d1[j] = pk[2 * j] - pk[2 * j + 1];
    }
    float s2[4], t2[4], u2[4];
#pragma unroll
    for (int mI = 0; mI < 4; ++mI) {
        s2[mI] = s1[2 * mI] + s1[2 * mI + 1];
        t2[mI] = s1[2 * mI] - s1[2 * mI + 1];
        u2[mI] = d1[2 * mI] - d1[2 * mI + 1];
    }
    const float o0 = (s2[0] + s2[1]) - (s2[2] + s2[3]);
    const float o1 = (s2[0] - s2[1]) - (s2[2] - s2[3]);
    const float o2 = (t2[0] - t2[1]) - (t2[2] - t2[3]);
    const float o3 = (u2[0] - u2[1]) - (u2[2] - u2[3]);

    reinterpret_cast<float4*>(out)[i] = make_float4(o0, o1, o2, o3);
}

extern "C" void kernel_launch(void* const* d_in, const int* in_sizes, int n_in,
                              void* d_out, int out_size, void* d_ws, size_t ws_size,
                              hipStream_t stream) {
    const float* patch  = (const float*)d_in[0];
    const float* params = (const float*)d_in[1];
    float* out = (float*)d_out;
    float* ws  = (float*)d_ws;
    const int B = in_sizes[0] / 4;

    vqc_setup<<<1, 16, 0, stream>>>(params, ws);

    const int block = 256;
    const int grid = (B + block - 1) / block;
    vqc_main<<<grid, block, 0, stream>>>(patch, ws, out, B);
}